// Round 2
// baseline (77.949 us; speedup 1.0000x reference)
//
#include <hip/hip_runtime.h>
#include <math.h>

// B=8, N=2048, coords [B,N,3] f32. LDDT loss, upper-triangle formulation:
// both distance matrices are symmetric, so num/den over {j>i} gives the same
// ratio as over all ordered pairs; j>i also excludes the diagonal (the
// reference's true_d > 1e-8 test is vacuous for distinct points).
//
// V3: j-tile broadcast via v_readlane (forced with __builtin_amdgcn_readlane
// -- V2 showed the compiler will NOT scalarize uniform global loads, and V1's
// LDS reads put ~12 cyc/wave/j on the LDS pipe). Each lane owns one j-point
// in 6 VGPRs; the inner loop readlanes them into SGPRs (1 VALU op each, then
// free SGPR operands to the distance math). Bin counting via ballot+popcount
// runs on the SALU pipe, concurrent with VALU.
// Wave-level triangle skip: boundary tile k=c-4a vs wave w:
//   k<w: all j<i -> skip wave entirely; k==w: diagonal, check is jj>lane;
//   k>w: all j>i -> unchecked. Deletes 6/16 of boundary wave-runs.
constexpr int B  = 8;
constexpr int N  = 2048;
constexpr int TI = 256;        // i-points per block (== threads)
constexpr int TJ = 64;         // j-points per block (== one wave's lanes)
constexpr int TILES = 144;     // sum_{a=0..7} (32 - 4a): j-tiles with any j>i

__device__ __forceinline__ float rlane(float v, int l) {
    return __uint_as_float(__builtin_amdgcn_readlane(__float_as_uint(v), l));
}

template <bool CHECK>
__device__ __forceinline__ void inner_loop(
    float vjx, float vjy, float vjz,   // this lane's j-point (pred)
    float vux, float vuy, float vuz,   // this lane's j-point (true)
    float pix, float piy, float piz,
    float tix, float tiy, float tiz,
    int lane,
    unsigned& c0, unsigned& c1, unsigned& c2, unsigned& c3, unsigned& cd)
{
    #pragma unroll 16
    for (int jj = 0; jj < TJ; ++jj) {
        // broadcast lane jj's j-point to the whole wave: 6x v_readlane -> SGPRs
        float jx = rlane(vjx, jj), jy = rlane(vjy, jj), jz = rlane(vjz, jj);
        float ux = rlane(vux, jj), uy = rlane(vuy, jj), uz = rlane(vuz, jj);

        float dx = pix - jx, dy = piy - jy, dz = piz - jz;
        float pd2 = fmaf(dx, dx, fmaf(dy, dy, dz * dz));
        float ex = tix - ux, ey = tiy - uy, ez = tiz - uz;
        float td2 = fmaf(ex, ex, fmaf(ey, ey, ez * ez));

        // local mask (squared domain): true_d < 15
        unsigned long long m = __ballot(td2 < 225.0f);
        if (CHECK) m &= __ballot(jj > lane);   // diagonal tile: j>i <=> jj>lane

        float diff = fabsf(__builtin_amdgcn_sqrtf(pd2) - __builtin_amdgcn_sqrtf(td2));

        // cumulative bins: score = .5*[d<.5] + .25*[d<1] + .125*[d<2] + .125*[d<4]
        c0 += __popcll(m & __ballot(diff < 0.5f));
        c1 += __popcll(m & __ballot(diff < 1.0f));
        c2 += __popcll(m & __ballot(diff < 2.0f));
        c3 += __popcll(m & __ballot(diff < 4.0f));
        cd += __popcll(m);
    }
}

__global__ __launch_bounds__(TI) void lddt_partial(
    const float* __restrict__ pred,   // [B,N,3]
    const float* __restrict__ truec,  // [B,N,3]
    float* __restrict__ part)         // [B,TILES,2]
{
    const int b = blockIdx.y;
    // decode linear tile index -> (a = i-tile, k = j-subtile rel. index)
    int r = blockIdx.x, a = 0;
    while (r >= 32 - 4 * a) { r -= 32 - 4 * a; ++a; }
    const int k = r;                  // c = 4a + k, k in [0, 32-4a)
    const int i0 = a * TI;
    const int j0 = (4 * a + k) * TJ;
    const int t = threadIdx.x;
    const int w = t >> 6;
    const int lane = t & 63;

    unsigned c0 = 0, c1 = 0, c2 = 0, c3 = 0, cd = 0;

    if (k >= w) {                     // k<w: whole wave is j<i -> contribute 0
        const int i = i0 + t;
        const float* pi = pred  + ((size_t)b * N + i) * 3;
        const float* ti = truec + ((size_t)b * N + i) * 3;
        const float pix = pi[0], piy = pi[1], piz = pi[2];
        const float tix = ti[0], tiy = ti[1], tiz = ti[2];

        // this lane owns j-point j0+lane (each wave loads the full j-tile)
        const float* pj = pred  + ((size_t)b * N + j0 + lane) * 3;
        const float* tj = truec + ((size_t)b * N + j0 + lane) * 3;
        const float vjx = pj[0], vjy = pj[1], vjz = pj[2];
        const float vux = tj[0], vuy = tj[1], vuz = tj[2];

        if (k > w) {                  // strictly above diagonal: no check
            inner_loop<false>(vjx, vjy, vjz, vux, vuy, vuz,
                              pix, piy, piz, tix, tiy, tiz, lane,
                              c0, c1, c2, c3, cd);
        } else {                      // k == w: diagonal 64x64, jj>lane check
            inner_loop<true>(vjx, vjy, vjz, vux, vuy, vuz,
                             pix, piy, piz, tix, tiy, tiz, lane,
                             c0, c1, c2, c3, cd);
        }
    }

    // counters are wave-uniform (ballot-derived): lane 0 of each wave has them
    __shared__ float rnum[TI / 64];
    __shared__ float rden[TI / 64];
    if (lane == 0) {
        rnum[w] = 0.125f * (float)(4u * c0 + 2u * c1 + c2 + c3);
        rden[w] = (float)cd;
    }
    __syncthreads();

    if (t == 0) {
        float n = 0.0f, d = 0.0f;
        #pragma unroll
        for (int q = 0; q < TI / 64; ++q) { n += rnum[q]; d += rden[q]; }
        // plain store to this block's private slot -- NO atomics, no memset
        float* slot = part + ((size_t)b * TILES + blockIdx.x) * 2;
        slot[0] = n;
        slot[1] = d;
    }
}

// 512 threads = 8 waves; wave w reduces batch w's 144 slots.
__global__ __launch_bounds__(512) void lddt_reduce(
    const float* __restrict__ part,   // [B,TILES,2]
    float* __restrict__ out)          // [1]
{
    const int t = threadIdx.x;
    const int w = t >> 6;     // batch
    const int l = t & 63;

    float n = 0.0f, d = 0.0f;
    for (int s = l; s < TILES; s += 64) {
        const float* slot = part + ((size_t)w * TILES + s) * 2;
        n += slot[0];
        d += slot[1];
    }
    for (int off = 32; off > 0; off >>= 1) {
        n += __shfl_down(n, off, 64);
        d += __shfl_down(d, off, 64);
    }

    __shared__ float acc[B];
    if (l == 0) acc[w] = 1.0f - n / fmaxf(d, 1e-8f);
    __syncthreads();

    if (t == 0) {
        float s = 0.0f;
        #pragma unroll
        for (int b = 0; b < B; ++b) s += acc[b];
        out[0] = s / (float)B;
    }
}

extern "C" void kernel_launch(void* const* d_in, const int* in_sizes, int n_in,
                              void* d_out, int out_size, void* d_ws, size_t ws_size,
                              hipStream_t stream)
{
    const float* pred  = (const float*)d_in[0];
    const float* truec = (const float*)d_in[1];
    float* out  = (float*)d_out;
    float* part = (float*)d_ws;   // B*TILES*2 floats = 9216 B

    dim3 grid(TILES, B);
    lddt_partial<<<grid, TI, 0, stream>>>(pred, truec, part);
    lddt_reduce<<<1, 512, 0, stream>>>(part, out);
}

// Round 3
// 71.707 us; speedup vs baseline: 1.0871x; 1.0871x over previous
//
#include <hip/hip_runtime.h>
#include <math.h>

// B=8, N=2048, coords [B,N,3] f32. LDDT loss, upper-triangle formulation:
// both distance matrices are symmetric, so num/den over {j>i} gives the same
// ratio as over all ordered pairs; j>i also excludes the diagonal (the
// reference's true_d > 1e-8 test is vacuous for distinct points).
//
// V4 = V1 (best measured: LDS same-address broadcast, ballot+popcount
// counting) with two LDS-pipe / work reductions:
//  - packed j-tile: {px,py,pz,tx,ty,tz} interleaved -> 2 j-points per
//    3x ds_read_b128 (V1 paid 4 reads / 2 j). LDS pipe was the bottleneck
//    (~11.5us of ~14us): -25% LDS instructions.
//  - wave-level triangle skip (V3's sound part): boundary tile k vs wave w:
//    k<w: skip wave; k==w: diagonal, mask is the CONSTANT (1<<jj)-1 (2 SALU,
//    no extra ballot); k>w: unchecked. Cuts ~8% of total pair work.
// v_readlane broadcast (V3) and uniform-pointer loads (V2) both measured
// SLOWER than LDS broadcast -- do not revisit.
constexpr int B  = 8;
constexpr int N  = 2048;
constexpr int TI = 256;        // i-points per block (== threads)
constexpr int TJ = 64;         // j-points per block (== one wave)
constexpr int TILES = 144;     // sum_{a=0..7} (32 - 4a): j-tiles with any j>i

template <bool CHECK>
__device__ __forceinline__ void do_pair(
    float jx, float jy, float jz, float ux, float uy, float uz,
    float pix, float piy, float piz, float tix, float tiy, float tiz,
    int jj,
    unsigned& c0, unsigned& c1, unsigned& c2, unsigned& c3, unsigned& cd)
{
    float dx = pix - jx, dy = piy - jy, dz = piz - jz;
    float pd2 = fmaf(dx, dx, fmaf(dy, dy, dz * dz));
    float ex = tix - ux, ey = tiy - uy, ez = tiz - uz;
    float td2 = fmaf(ex, ex, fmaf(ey, ey, ez * ez));

    // local mask (squared domain): true_d < 15
    unsigned long long m = __ballot(td2 < 225.0f);
    // diagonal tile: j>i <=> jj>lane <=> lane in [0,jj) -> constant mask
    if (CHECK) m &= (jj < 64) ? ((1ull << jj) - 1ull) : ~0ull;

    float diff = fabsf(__builtin_amdgcn_sqrtf(pd2) - __builtin_amdgcn_sqrtf(td2));

    // cumulative bins: score = .5*[d<.5] + .25*[d<1] + .125*[d<2] + .125*[d<4]
    c0 += __popcll(m & __ballot(diff < 0.5f));
    c1 += __popcll(m & __ballot(diff < 1.0f));
    c2 += __popcll(m & __ballot(diff < 2.0f));
    c3 += __popcll(m & __ballot(diff < 4.0f));
    cd += __popcll(m);
}

template <bool CHECK>
__device__ __forceinline__ void inner_loop(
    const float4* __restrict__ s4,   // packed j-tile: 3 float4 per 2 j-points
    float pix, float piy, float piz,
    float tix, float tiy, float tiz,
    unsigned& c0, unsigned& c1, unsigned& c2, unsigned& c3, unsigned& cd)
{
    #pragma unroll 4
    for (int q = 0; q < TJ / 2; ++q) {
        // same address across all 64 lanes -> LDS broadcast, conflict-free
        float4 A = s4[3 * q + 0];   // {p0.x, p0.y, p0.z, t0.x}
        float4 Bq = s4[3 * q + 1];  // {t0.y, t0.z, p1.x, p1.y}
        float4 Cq = s4[3 * q + 2];  // {p1.z, t1.x, t1.y, t1.z}

        do_pair<CHECK>(A.x, A.y, A.z, A.w, Bq.x, Bq.y,
                       pix, piy, piz, tix, tiy, tiz, 2 * q,
                       c0, c1, c2, c3, cd);
        do_pair<CHECK>(Bq.z, Bq.w, Cq.x, Cq.y, Cq.z, Cq.w,
                       pix, piy, piz, tix, tiy, tiz, 2 * q + 1,
                       c0, c1, c2, c3, cd);
    }
}

__global__ __launch_bounds__(TI) void lddt_partial(
    const float* __restrict__ pred,   // [B,N,3]
    const float* __restrict__ truec,  // [B,N,3]
    float* __restrict__ part)         // [B,TILES,2]
{
    const int b = blockIdx.y;
    // decode linear tile index -> (a = i-tile, k = j-subtile rel. index)
    int r = blockIdx.x, a = 0;
    while (r >= 32 - 4 * a) { r -= 32 - 4 * a; ++a; }
    const int k = r;                  // c = 4a + k, k in [0, 32-4a)
    const int i0 = a * TI;
    const int j0 = (4 * a + k) * TJ;
    const int t = threadIdx.x;
    const int w = t >> 6;
    const int lane = t & 63;

    // packed j-tile: sj[6*j .. 6*j+5] = {px,py,pz,tx,ty,tz} of point j0+j
    __shared__ float sj[TJ * 6];
    if (t < TJ) {
        const float* pp = pred  + ((size_t)b * N + j0 + t) * 3;
        const float* tp = truec + ((size_t)b * N + j0 + t) * 3;
        sj[6 * t + 0] = pp[0];
        sj[6 * t + 1] = pp[1];
        sj[6 * t + 2] = pp[2];
        sj[6 * t + 3] = tp[0];
        sj[6 * t + 4] = tp[1];
        sj[6 * t + 5] = tp[2];
    }
    __syncthreads();

    unsigned c0 = 0, c1 = 0, c2 = 0, c3 = 0, cd = 0;

    if (k >= w) {                     // k<w: whole wave is j<i -> zero
        const int i = i0 + t;
        const float* pi = pred  + ((size_t)b * N + i) * 3;
        const float* ti = truec + ((size_t)b * N + i) * 3;
        const float pix = pi[0], piy = pi[1], piz = pi[2];
        const float tix = ti[0], tiy = ti[1], tiz = ti[2];
        const float4* s4 = reinterpret_cast<const float4*>(sj);

        if (k > w) {                  // strictly above diagonal: no check
            inner_loop<false>(s4, pix, piy, piz, tix, tiy, tiz,
                              c0, c1, c2, c3, cd);
        } else {                      // k == w: diagonal 64x64 block
            inner_loop<true>(s4, pix, piy, piz, tix, tiy, tiz,
                             c0, c1, c2, c3, cd);
        }
    }

    // counters are wave-uniform (ballot-derived): lane 0 of each wave has them
    __shared__ float rnum[TI / 64];
    __shared__ float rden[TI / 64];
    if (lane == 0) {
        rnum[w] = 0.125f * (float)(4u * c0 + 2u * c1 + c2 + c3);
        rden[w] = (float)cd;
    }
    __syncthreads();

    if (t == 0) {
        float n = 0.0f, d = 0.0f;
        #pragma unroll
        for (int q = 0; q < TI / 64; ++q) { n += rnum[q]; d += rden[q]; }
        // plain store to this block's private slot -- NO atomics, no memset
        float* slot = part + ((size_t)b * TILES + blockIdx.x) * 2;
        slot[0] = n;
        slot[1] = d;
    }
}

// 512 threads = 8 waves; wave w reduces batch w's 144 slots.
__global__ __launch_bounds__(512) void lddt_reduce(
    const float* __restrict__ part,   // [B,TILES,2]
    float* __restrict__ out)          // [1]
{
    const int t = threadIdx.x;
    const int w = t >> 6;     // batch
    const int l = t & 63;

    float n = 0.0f, d = 0.0f;
    for (int s = l; s < TILES; s += 64) {
        const float* slot = part + ((size_t)w * TILES + s) * 2;
        n += slot[0];
        d += slot[1];
    }
    for (int off = 32; off > 0; off >>= 1) {
        n += __shfl_down(n, off, 64);
        d += __shfl_down(d, off, 64);
    }

    __shared__ float acc[B];
    if (l == 0) acc[w] = 1.0f - n / fmaxf(d, 1e-8f);
    __syncthreads();

    if (t == 0) {
        float s = 0.0f;
        #pragma unroll
        for (int b = 0; b < B; ++b) s += acc[b];
        out[0] = s / (float)B;
    }
}

extern "C" void kernel_launch(void* const* d_in, const int* in_sizes, int n_in,
                              void* d_out, int out_size, void* d_ws, size_t ws_size,
                              hipStream_t stream)
{
    const float* pred  = (const float*)d_in[0];
    const float* truec = (const float*)d_in[1];
    float* out  = (float*)d_out;
    float* part = (float*)d_ws;   // B*TILES*2 floats = 9216 B

    dim3 grid(TILES, B);
    lddt_partial<<<grid, TI, 0, stream>>>(pred, truec, part);
    lddt_reduce<<<1, 512, 0, stream>>>(part, out);
}